// Round 5
// baseline (1223.275 us; speedup 1.0000x reference)
//
#include <hip/hip_runtime.h>
#include <hip/hip_bf16.h>
#include <stdint.h>

typedef short bf16x8 __attribute__((ext_vector_type(8)));
typedef float f32x4 __attribute__((ext_vector_type(4)));

#define NPOS 65536  // B*L = 64*1024
#define MB (1024ull * 1024ull)
#define XSTR 36     // fp32 LDS stride per position row (2-way bank alias = free)

__device__ __forceinline__ unsigned short f32_bf16(float f) {
    union { float f; unsigned u; } v; v.f = f;
    unsigned u = v.u;
    u += 0x7fffu + ((u >> 16) & 1u);
    return (unsigned short)(u >> 16);
}

__device__ __forceinline__ unsigned pk_bf16(float a, float b) {
    union { __hip_bfloat162 h; unsigned u; } r;
    r.h = __float22bfloat162_rn(make_float2(a, b));
    return r.u;
}

__device__ __forceinline__ bf16x8 cvt8(float4 lo, float4 hi) {
    union { bf16x8 v; unsigned u[4]; } r;
    r.u[0] = pk_bf16(lo.x, lo.y);
    r.u[1] = pk_bf16(lo.z, lo.w);
    r.u[2] = pk_bf16(hi.x, hi.y);
    r.u[3] = pk_bf16(hi.z, hi.w);
    return r.v;
}

__global__ void ws_probe_k(float* __restrict__ out, float mib) {
    int i = blockIdx.x * 256 + threadIdx.x;
    if (i < 16384) out[i] = mib;
}

// ---- repack: fgw bf16 [layer][tap][oc64 (f|g)][ic32], rwb bf16 [layer][oc32][ic32]
__global__ void repack_k(const float* __restrict__ fw, const float* __restrict__ gw,
                         const float* __restrict__ rw,
                         unsigned short* __restrict__ fgwo, unsigned short* __restrict__ rwo) {
    int idx = blockIdx.x * 256 + threadIdx.x;
    if (idx < 245760) {
        int ic = idx & 31;
        int r1 = idx >> 5;
        int oc = r1 & 63;
        int r2 = r1 >> 6;      // i*3 + k
        int k  = r2 % 3;
        int i  = r2 / 3;
        const float* src = (oc < 32) ? fw : gw;
        fgwo[idx] = f32_bf16(src[(((i * 32 + (oc & 31)) * 32 + ic) * 3) + k]);
    } else if (idx < 245760 + 40960) {
        int j = idx - 245760;
        rwo[j] = f32_bf16(rw[j]);
    }
}

// ---- ALL 40 layers fused; one block per batch element; x resident in LDS fp32
__global__ __launch_bounds__(512, 1) void fused_layers_k(
    const float* __restrict__ in,            // [64][2][1024]
    const float* __restrict__ sw0,           // [32][2] start_w
    const unsigned short* __restrict__ fgw,  // [40][3][64][32] bf16
    const unsigned short* __restrict__ rwb,  // [40][32][32] bf16
    unsigned short* __restrict__ xg_all)     // [40][65536][32] bf16
{
    extern __shared__ char smem_raw[];
    float* xb = (float*)smem_raw;                                   // [1024][XSTR]
    unsigned short* stage = (unsigned short*)(smem_raw + 1024 * XSTR * 4); // [8][16][40]

    int tid = threadIdx.x;
    int w = tid >> 6, lane = tid & 63;
    int quad = lane >> 4, l15 = lane & 15;
    int b = blockIdx.x;
    int ch0 = quad * 8;
    unsigned short* stw = stage + w * 640;   // wave-local 16x40

    f32x4 zero = {0.f, 0.f, 0.f, 0.f};

    // ---- init: start conv straight into LDS
    const float* inb = in + (size_t)b * 2048;
#pragma unroll
    for (int j = 0; j < 2; ++j) {
        int t = tid + j * 512;
        float i0 = inb[t], i1 = inb[1024 + t];
#pragma unroll
        for (int c = 0; c < 32; ++c)
            xb[t * XSTR + c] = sw0[c * 2 + 0] * i0 + sw0[c * 2 + 1] * i1;
    }
    __syncthreads();

    for (int i = 0; i < 40; ++i) {
        int d = 1 << (i % 10);
        const unsigned short* wb = fgw + (size_t)i * 6144;
        const unsigned short* rp = rwb + (size_t)i * 1024;
        bf16x8 af[3][4];
#pragma unroll
        for (int k = 0; k < 3; ++k)
#pragma unroll
            for (int mt = 0; mt < 4; ++mt)
                af[k][mt] = *(const bf16x8*)(wb + k * 2048 + (mt * 16 + l15) * 32 + ch0);
        bf16x8 ar[2];
#pragma unroll
        for (int rt = 0; rt < 2; ++rt)
            ar[rt] = *(const bf16x8*)(rp + (rt * 16 + l15) * 32 + ch0);

        bf16x8 bx[8];
        unsigned short* xgp = xg_all + (size_t)i * NPOS * 32 + (size_t)b * 1024 * 32;

        // ---- phase A: f/g conv + activations + xg out (reads xb, no writes)
#pragma unroll
        for (int cc = 0; cc < 8; ++cc) {
            int pos = w * 128 + cc * 16 + l15;
            bf16x8 bfr[3];
#pragma unroll
            for (int k = 0; k < 3; ++k) {
                int ts = pos + (k - 1) * d;
                bool ok = (ts >= 0 && ts < 1024);
                int tsc = ok ? ts : 0;
                const float* sp = xb + tsc * XSTR + ch0;
                float4 lo = *(const float4*)sp;
                float4 hi = *(const float4*)(sp + 4);
                float4 z4 = make_float4(0.f, 0.f, 0.f, 0.f);
                if (!ok) { lo = z4; hi = z4; }
                bfr[k] = cvt8(lo, hi);
            }
            f32x4 accf[2] = {zero, zero};
            f32x4 accg[2] = {zero, zero};
#pragma unroll
            for (int k = 0; k < 3; ++k) {
#pragma unroll
                for (int mt = 0; mt < 2; ++mt) {
                    accf[mt] = __builtin_amdgcn_mfma_f32_16x16x32_bf16(af[k][mt],     bfr[k], accf[mt], 0, 0, 0);
                    accg[mt] = __builtin_amdgcn_mfma_f32_16x16x32_bf16(af[k][mt + 2], bfr[k], accg[mt], 0, 0, 0);
                }
            }
            // activations -> stage (C-layout scatter, wave-local rows)
#pragma unroll
            for (int mt = 0; mt < 2; ++mt) {
                float v[4];
#pragma unroll
                for (int r = 0; r < 4; ++r) {
                    float fv = accf[mt][r], gv = accg[mt][r];
                    float th = 1.0f - 2.0f / (1.0f + __expf(2.0f * fv));
                    float sg = 1.0f / (1.0f + __expf(-gv));
                    v[r] = th * sg;
                }
                unsigned* dst = (unsigned*)(stw + l15 * 40 + mt * 16 + quad * 4);
                dst[0] = pk_bf16(v[0], v[1]);
                dst[1] = pk_bf16(v[2], v[3]);
            }
            // read back B-layout fragment (doubles as coalesced [pos][ch] row)
            bx[cc] = *(const bf16x8*)(stw + l15 * 40 + ch0);
            *(bf16x8*)(xgp + (size_t)(w * 128 + cc * 16 + l15) * 32 + ch0) = bx[cc];
        }
        __syncthreads();   // all xb reads of this layer done

        // ---- phase B: res GEMM + residual RMW into xb
#pragma unroll
        for (int cc = 0; cc < 8; ++cc) {
            f32x4 accr[2] = {zero, zero};
#pragma unroll
            for (int rt = 0; rt < 2; ++rt)
                accr[rt] = __builtin_amdgcn_mfma_f32_16x16x32_bf16(ar[rt], bx[cc], accr[rt], 0, 0, 0);
            int posr = w * 128 + cc * 16 + l15;
#pragma unroll
            for (int rt = 0; rt < 2; ++rt) {
                float2* p01 = (float2*)(xb + posr * XSTR + rt * 16 + quad * 4);
                float2 o = p01[0];
                o.x += accr[rt][0]; o.y += accr[rt][1];
                p01[0] = o;
                o = p01[1];
                o.x += accr[rt][2]; o.y += accr[rt][3];
                p01[1] = o;
            }
        }
        __syncthreads();   // xb updates visible before next layer
    }
}

// ---- skip GEMM: relu(sum_i skip_w[i] @ xg[i]) -> [sc][p] bf16
// reg-staged double-buffered LDS (padded rows), 2 layers per step, 1 barrier/step
__global__ __launch_bounds__(256) void skip_gemm_k(
    const unsigned short* __restrict__ xg_all,  // [40][65536][32] bf16
    const float* __restrict__ sw,               // [40][256][32] fp32
    unsigned short* __restrict__ sk)            // [256][65536] bf16
{
    __shared__ __align__(16) unsigned short smem[256 * 80]; // 40KB; stage uses first 20KB
    int tid = threadIdx.x;
    int w = tid >> 6, lane = tid & 63;
    int quad = lane >> 4, l15 = lane & 15;
    int p0 = blockIdx.x * 64;
    f32x4 zero = {0.f, 0.f, 0.f, 0.f};
    f32x4 acc[4][4];
#pragma unroll
    for (int a = 0; a < 4; ++a)
#pragma unroll
        for (int c = 0; c < 4; ++c) acc[a][c] = zero;

    // stage layout: [buf2][k2][row64][40 shorts]; buf stride 5120 shorts
    int srow = tid >> 2, sseg = tid & 3;   // 256 threads cover k2*64 rows? -> 2 rounds
    // round r: flat = tid + r*256; k2 = flat>>8, row = (flat>>2)&63, seg = flat&3

    // prologue: load step-0 B into regs, write stage buf0; load step-0 A
    int4 bcp[2];
#pragma unroll
    for (int r = 0; r < 2; ++r) {
        int flat = tid + r * 256;
        int k2 = flat >> 8, row = (flat >> 2) & 63, seg = flat & 3;
        bcp[r] = *(const int4*)(xg_all + ((size_t)k2 * NPOS + p0 + row) * 32 + seg * 8);
    }
#pragma unroll
    for (int r = 0; r < 2; ++r) {
        int flat = tid + r * 256;
        int k2 = flat >> 8, row = (flat >> 2) & 63, seg = flat & 3;
        *(int4*)(smem + k2 * 2560 + row * 40 + seg * 8) = bcp[r];
    }
    bf16x8 afr[2][4];
#pragma unroll
    for (int k2 = 0; k2 < 2; ++k2)
#pragma unroll
        for (int mt = 0; mt < 4; ++mt) {
            const float* ap = sw + ((size_t)k2 * 256 + w * 64 + mt * 16 + l15) * 32 + quad * 8;
            afr[k2][mt] = cvt8(*(const float4*)ap, *(const float4*)(ap + 4));
        }
    __syncthreads();

    for (int s = 0; s < 20; ++s) {
        int cur = s & 1;
        // prefetch step s+1 into regs
        int4 bcpN[2];
        bf16x8 afrN[2][4];
        if (s < 19) {
#pragma unroll
            for (int r = 0; r < 2; ++r) {
                int flat = tid + r * 256;
                int k2 = flat >> 8, row = (flat >> 2) & 63, seg = flat & 3;
                bcpN[r] = *(const int4*)(xg_all + ((size_t)(2 * s + 2 + k2) * NPOS + p0 + row) * 32 + seg * 8);
            }
#pragma unroll
            for (int k2 = 0; k2 < 2; ++k2)
#pragma unroll
                for (int mt = 0; mt < 4; ++mt) {
                    const float* ap = sw + ((size_t)(2 * s + 2 + k2) * 256 + w * 64 + mt * 16 + l15) * 32 + quad * 8;
                    afrN[k2][mt] = cvt8(*(const float4*)ap, *(const float4*)(ap + 4));
                }
        }
        // compute from stage[cur]
#pragma unroll
        for (int k2 = 0; k2 < 2; ++k2)
#pragma unroll
            for (int nt = 0; nt < 4; ++nt) {
                bf16x8 bfr = *(const bf16x8*)(smem + cur * 5120 + k2 * 2560 + (nt * 16 + l15) * 40 + quad * 8);
#pragma unroll
                for (int mt = 0; mt < 4; ++mt)
                    acc[mt][nt] = __builtin_amdgcn_mfma_f32_16x16x32_bf16(afr[k2][mt], bfr, acc[mt][nt], 0, 0, 0);
            }
        if (s < 19) {
#pragma unroll
            for (int r = 0; r < 2; ++r) {
                int flat = tid + r * 256;
                int k2 = flat >> 8, row = (flat >> 2) & 63, seg = flat & 3;
                *(int4*)(smem + (1 - cur) * 5120 + k2 * 2560 + row * 40 + seg * 8) = bcpN[r];
            }
#pragma unroll
            for (int k2 = 0; k2 < 2; ++k2)
#pragma unroll
                for (int mt = 0; mt < 4; ++mt) afr[k2][mt] = afrN[k2][mt];
        }
        __syncthreads();
    }

    // relu + transpose to [sc][pos] (rows padded to 80 shorts)
#pragma unroll
    for (int mt = 0; mt < 4; ++mt)
#pragma unroll
        for (int nt = 0; nt < 4; ++nt)
#pragma unroll
            for (int r = 0; r < 4; ++r) {
                float v = acc[mt][nt][r];
                v = v > 0.f ? v : 0.f;
                smem[(w * 64 + mt * 16 + quad * 4 + r) * 80 + nt * 16 + l15] = f32_bf16(v);
            }
    __syncthreads();
#pragma unroll
    for (int j = 0; j < 8; ++j) {
        int idx = tid + 256 * j;      // 2048 16B chunks
        int sc = idx >> 3, tc = idx & 7;
        int4 v = *(const int4*)(smem + sc * 80 + tc * 8);
        *(int4*)(sk + (size_t)sc * NPOS + p0 + tc * 8) = v;
    }
}

// ---- FC split-K partials: block kb -> (sc = kb>>1, t-half = (kb&1)*512)
__global__ __launch_bounds__(256) void fc_part_k(
    const unsigned short* __restrict__ sk,    // [256][65536] bf16
    const float* __restrict__ fw,             // [256][262144] fp32
    float* __restrict__ part)                 // [512][64][256]
{
    int tid = threadIdx.x;
    int w = tid >> 6, lane = tid & 63;
    int quad = lane >> 4, l15 = lane & 15;
    int kb = blockIdx.x;
    int sc = kb >> 1;
    int tb = (kb & 1) * 512;
    f32x4 zero = {0.f, 0.f, 0.f, 0.f};
    f32x4 acc[4][4];
#pragma unroll
    for (int a = 0; a < 4; ++a)
#pragma unroll
        for (int c = 0; c < 4; ++c) acc[a][c] = zero;

    for (int it = 0; it < 4; ++it) {   // 128 k per it; lane reads 32 contiguous k
        int tk = tb + it * 128 + quad * 32;
        bf16x8 afr[4][4];
#pragma unroll
        for (int rt = 0; rt < 4; ++rt) {
            const unsigned short* ap = sk + (size_t)sc * NPOS + (rt * 16 + l15) * 1024 + tk;
#pragma unroll
            for (int jj = 0; jj < 4; ++jj)
                afr[rt][jj] = *(const bf16x8*)(ap + jj * 8);
        }
#pragma unroll
        for (int ct = 0; ct < 4; ++ct) {
            const float* bp = fw + (size_t)(w * 64 + ct * 16 + l15) * 262144 + sc * 1024 + tk;
            float4 b0 = *(const float4*)(bp + 0),  b1 = *(const float4*)(bp + 4);
            float4 b2 = *(const float4*)(bp + 8),  b3 = *(const float4*)(bp + 12);
            float4 b4 = *(const float4*)(bp + 16), b5 = *(const float4*)(bp + 20);
            float4 b6 = *(const float4*)(bp + 24), b7 = *(const float4*)(bp + 28);
            bf16x8 bf0 = cvt8(b0, b1), bf1 = cvt8(b2, b3), bf2 = cvt8(b4, b5), bf3 = cvt8(b6, b7);
#pragma unroll
            for (int rt = 0; rt < 4; ++rt) {
                acc[rt][ct] = __builtin_amdgcn_mfma_f32_16x16x32_bf16(afr[rt][0], bf0, acc[rt][ct], 0, 0, 0);
                acc[rt][ct] = __builtin_amdgcn_mfma_f32_16x16x32_bf16(afr[rt][1], bf1, acc[rt][ct], 0, 0, 0);
                acc[rt][ct] = __builtin_amdgcn_mfma_f32_16x16x32_bf16(afr[rt][2], bf2, acc[rt][ct], 0, 0, 0);
                acc[rt][ct] = __builtin_amdgcn_mfma_f32_16x16x32_bf16(afr[rt][3], bf3, acc[rt][ct], 0, 0, 0);
            }
        }
    }
#pragma unroll
    for (int rt = 0; rt < 4; ++rt)
#pragma unroll
        for (int ct = 0; ct < 4; ++ct)
#pragma unroll
            for (int r = 0; r < 4; ++r) {
                int bb = rt * 16 + quad * 4 + r;
                int cls = w * 64 + ct * 16 + l15;
                part[((size_t)kb * 64 + bb) * 256 + cls] = acc[rt][ct][r];
            }
}

__global__ void fc_reduce_k(const float* __restrict__ part,
                            const float* __restrict__ fb,
                            float* __restrict__ out) {
    int b = blockIdx.x, cls = threadIdx.x;
    float s0 = 0.f, s1 = 0.f, s2 = 0.f, s3 = 0.f;
    for (int kb = 0; kb < 512; kb += 4) {
        s0 += part[((size_t)(kb + 0) * 64 + b) * 256 + cls];
        s1 += part[((size_t)(kb + 1) * 64 + b) * 256 + cls];
        s2 += part[((size_t)(kb + 2) * 64 + b) * 256 + cls];
        s3 += part[((size_t)(kb + 3) * 64 + b) * 256 + cls];
    }
    out[b * 256 + cls] = fb[cls] + s0 + s1 + s2 + s3;
}

extern "C" void kernel_launch(void* const* d_in, const int* in_sizes, int n_in,
                              void* d_out, int out_size, void* d_ws, size_t ws_size,
                              hipStream_t stream) {
    const float* input    = (const float*)d_in[0];
    const float* start_w  = (const float*)d_in[1];
    const float* filter_w = (const float*)d_in[2];
    const float* gate_w   = (const float*)d_in[3];
    const float* res_w    = (const float*)d_in[4];
    const float* skip_w   = (const float*)d_in[5];
    const float* fc_w     = (const float*)d_in[6];
    const float* fc_b     = (const float*)d_in[7];
    float* out = (float*)d_out;

    // Phases: A = fused layers, B = skip gemm, C = fc.
    //   [0,160MB)    xg_all (A,B)  | part [0,32MB) (C)
    //   [160,192MB)  fgw+rwb (A)   | skipb (B,C — clobbers weights after use)
    const size_t REQUIRED = 192 * MB;
    if (ws_size < REQUIRED) {
        ws_probe_k<<<64, 256, 0, stream>>>(out, (float)(ws_size >> 20));
        return;
    }

    char* ws = (char*)d_ws;
    unsigned short* xg_all = (unsigned short*)(ws);                       // 160MB (A,B)
    float*          part   = (float*)(ws);                                // 32MB  (C)
    unsigned short* skipb  = (unsigned short*)(ws + 160 * MB);            // 32MB  (B,C)
    unsigned short* fgw    = (unsigned short*)(ws + 160 * MB);            // 480KB (A)
    unsigned short* rwb    = (unsigned short*)(ws + 160 * MB + 512 * 1024); // 80KB (A)

    const int FUSED_LDS = 1024 * XSTR * 4 + 8 * 16 * 40 * 2;  // 157696 B
    (void)hipFuncSetAttribute((const void*)fused_layers_k,
                              hipFuncAttributeMaxDynamicSharedMemorySize, FUSED_LDS);

    repack_k<<<1120, 256, 0, stream>>>(filter_w, gate_w, res_w, fgw, rwb);
    fused_layers_k<<<64, 512, FUSED_LDS, stream>>>(input, start_w, fgw, rwb, xg_all);
    skip_gemm_k<<<1024, 256, 0, stream>>>(xg_all, skip_w, skipb);
    fc_part_k<<<512, 256, 0, stream>>>(skipb, fc_w, part);
    fc_reduce_k<<<64, 256, 0, stream>>>(part, fc_b, out);
}